// Round 1
// 1005.510 us; speedup vs baseline: 1.0410x; 1.0410x over previous
//
#include <hip/hip_runtime.h>
#include <hip/hip_fp16.h>

typedef __attribute__((ext_vector_type(8))) _Float16 half8;
typedef __attribute__((ext_vector_type(4))) _Float16 half4;
typedef __attribute__((ext_vector_type(4))) float float4v;

#define NPIX 16384  // 128*128

__device__ inline half8 h8zero() {
    half8 z = {(_Float16)0, (_Float16)0, (_Float16)0, (_Float16)0,
               (_Float16)0, (_Float16)0, (_Float16)0, (_Float16)0};
    return z;
}

// ---------------- weight packing into MFMA B-fragment order ----------------
// conv packed layout: per conv, idx = ((nt*18 + kc)*64 + lane)*8 + j
//   k = kc*32 + (lane>>4)*8 + j  with k = ij*64 + c (shift-major), n = nt*16 + (lane&15)
__global__ void pack_conv_w(const float* __restrict__ src, _Float16* __restrict__ dst,
                            int nconv) {
    int idx = blockIdx.x * 256 + threadIdx.x;
    if (idx >= nconv * 36864) return;
    int ci = idx / 36864;
    int e  = idx % 36864;
    int j = e & 7;
    int lane = (e >> 3) & 63;
    int kcnt = e >> 9;               // nt*18 + kc
    int kc = kcnt % 18;
    int nt = kcnt / 18;
    int k = kc * 32 + (lane >> 4) * 8 + j;
    int n = nt * 16 + (lane & 15);
    int ij = k >> 6, c = k & 63;
    dst[idx] = (_Float16)src[ci * 36864 + (n * 64 + c) * 9 + ij];
}

// stage-A (mw0[:576]) pack: same as conv but N=256, source is [k=c*9+ij][n]
__global__ void pack_w0(const float* __restrict__ mw0, _Float16* __restrict__ dst) {
    int idx = blockIdx.x * 256 + threadIdx.x;
    if (idx >= 147456) return;
    int j = idx & 7;
    int lane = (idx >> 3) & 63;
    int kcnt = idx >> 9;             // nt*18 + kc, nt<16
    int kc = kcnt % 18;
    int nt = kcnt / 18;
    int k = kc * 32 + (lane >> 4) * 8 + j;
    int n = nt * 16 + (lane & 15);
    int ij = k >> 6, c = k & 63;
    dst[idx] = (_Float16)mw0[(c * 9 + ij) * 256 + n];
}

// MLP hidden weights (mw1..mw3) + padded mw4: layer layout ((nt*8+kc)*64+lane)*8+j
__global__ void pack_mlp(const float* __restrict__ w1, const float* __restrict__ w2,
                         const float* __restrict__ w3, const float* __restrict__ w4,
                         _Float16* __restrict__ dst) {
    int idx = blockIdx.x * 256 + threadIdx.x;
    if (idx >= 200704) return;
    if (idx < 196608) {
        int l = idx / 65536;
        int e = idx % 65536;
        int j = e & 7;
        int lane = (e >> 3) & 63;
        int kcnt = e >> 9;           // nt*8 + kc
        int kc = kcnt & 7, nt = kcnt >> 3;
        int k = kc * 32 + (lane >> 4) * 8 + j;
        int n = nt * 16 + (lane & 15);
        const float* w = (l == 0) ? w1 : ((l == 1) ? w2 : w3);
        dst[idx] = (_Float16)w[k * 256 + n];
    } else {
        int e = idx - 196608;        // < 4096, nt==0
        int j = e & 7;
        int lane = (e >> 3) & 63;
        int kc = e >> 9;
        int k = kc * 32 + (lane >> 4) * 8 + j;
        int n = lane & 15;
        dst[idx] = (n < 3) ? (_Float16)w4[k * 3 + n] : (_Float16)0.0f;
    }
}

// b0' = mb0 + q_cell @ mw0[578:580], q_cell = (0.5, 0.5)
__global__ void make_b0p(const float* __restrict__ mb0, const float* __restrict__ mw0,
                         float* __restrict__ b0p) {
    int t = threadIdx.x;
    b0p[t] = mb0[t] + 0.5f * (mw0[578 * 256 + t] + mw0[579 * 256 + t]);
}

// ---------------- head conv (Cin=3, direct fp32) ----------------
__global__ void head_conv(const float* __restrict__ x, const float* __restrict__ w,
                          const float* __restrict__ b, _Float16* __restrict__ h0) {
    int idx = blockIdx.x * 256 + threadIdx.x;   // p*64 + o
    int o = idx & 63, p = idx >> 6;
    int py = p >> 7, px = p & 127;
    float acc = b[o];
    #pragma unroll
    for (int c = 0; c < 3; ++c)
        #pragma unroll
        for (int i = 0; i < 3; ++i)
            #pragma unroll
            for (int jj = 0; jj < 3; ++jj) {
                int y = py + i - 1, xx = px + jj - 1;
                if (y >= 0 && y < 128 && xx >= 0 && xx < 128)
                    acc += x[c * 16384 + y * 128 + xx] * w[((o * 3 + c) * 3 + i) * 3 + jj];
            }
    h0[idx] = (_Float16)acc;
}

// ---------------- 3x3 conv as shifted-window implicit GEMM (MFMA) ----------------
// Restructured: each wave owns ONE nt (16 couts) with the 18 B-fragments held in
// VGPRs, and iterates MTPER m-tiles (16 pixels each). This removes the per-m-tile
// B re-read (73 MB -> 37 MB L2/conv) and raises occupancy 4 -> 8 waves/CU.
// NTOT==4 : grid = 1024/MTPER blocks, nt = wave,           mt0 = blk*MTPER
// NTOT==16: grid = 4*(1024/MTPER),    nt = (blk&3)*4+wave, mt0 = (blk>>2)*MTPER
template <int NTOT, int MTPER, bool RELU, bool RES, bool F32OUT>
__global__ __launch_bounds__(256, 2)
void conv_mfma_r(const _Float16* __restrict__ img, const _Float16* __restrict__ pw,
                 const float* __restrict__ bias, const _Float16* res,
                 _Float16* outh, float* outf) {
    int wave = threadIdx.x >> 6, lane = threadIdx.x & 63;
    int q = lane >> 4, r = lane & 15;
    int nt, mt0;
    if constexpr (NTOT == 4) {
        nt = wave;
        mt0 = blockIdx.x * MTPER;
    } else {
        nt = (blockIdx.x & 3) * 4 + wave;
        mt0 = (blockIdx.x >> 2) * MTPER;
    }

    half8 B[18];
    #pragma unroll
    for (int kc = 0; kc < 18; ++kc)
        B[kc] = *(const half8*)(pw + (((nt * 18 + kc) * 64 + lane) << 3));

    int n = nt * 16 + r;
    float bv = bias[n];

    #pragma unroll
    for (int mi = 0; mi < MTPER; ++mi) {
        int mt = mt0 + mi;
        int p0 = mt * 16;
        int py = p0 >> 7;
        int pxl = (p0 & 127) + r;
        float4v acc = {0.f, 0.f, 0.f, 0.f};
        #pragma unroll
        for (int kc = 0; kc < 18; ++kc) {
            int ij = kc >> 1;
            int di = ij / 3 - 1;
            int dj = ij - (ij / 3) * 3 - 1;
            int cb = (kc & 1) * 32 + q * 8;
            int yy = py + di, xx = pxl + dj;
            half8 a = h8zero();
            if (yy >= 0 && yy < 128 && xx >= 0 && xx < 128)
                a = *(const half8*)(img + ((yy << 7) + xx) * 64 + cb);
            acc = __builtin_amdgcn_mfma_f32_16x16x32_f16(a, B[kc], acc, 0, 0, 0);
        }
        #pragma unroll
        for (int reg = 0; reg < 4; ++reg) {
            int p = p0 + q * 4 + reg;
            float v = acc[reg] + bv;
            if (RES) v += (float)res[p * (NTOT * 16) + n];
            if (RELU) v = fmaxf(v, 0.f);
            if (F32OUT) outf[p * (NTOT * 16) + n] = v;
            else        outh[p * (NTOT * 16) + n] = (_Float16)v;
        }
    }
}

// ---------------- fused LIIF MLP + ensembling ----------------
// Block: 256 thr (4 waves) = 16 output pixels = 64 samples (s = lp*4 + rc).
// act in LDS, FRAGMENT-MAJOR layout: element (row,col) lives at
//   (((row>>4)*8 + (col>>5))*64 + ((col>>3)&3)*16 + (row&15))*8 + (col&7)
// so every A-fragment ds_read_b128 is base + lane*16B (lane-linear, conflict-free).
__global__ __launch_bounds__(256, 3)
void mlp_kernel(const float* __restrict__ apre, const float* __restrict__ mw0,
                const float* __restrict__ mb1, const float* __restrict__ mb2,
                const float* __restrict__ mb3, const float* __restrict__ mb4,
                const _Float16* __restrict__ pwm, const _Float16* __restrict__ pw4,
                float* __restrict__ out) {
    __shared__ _Float16 act[16384];        // 64 x 256, fragment-major (32 KB)
    __shared__ float sArea[64], sRelH[64], sRelW[64];
    __shared__ int sCell[64];
    __shared__ float sWh[256], sWw[256];

    int t = threadIdx.x;
    int p0 = blockIdx.x << 4;

    if (t < 64) {
        int lp = t >> 2, rc = t & 3;
        int p = p0 + lp;
        int oh = p >> 9, ow = p & 511;
        float sh = (oh + 0.5f) * (2.0f / 512.0f) - 1.0f;
        float sw = (ow + 0.5f) * (2.0f / 512.0f) - 1.0f;
        float gh = sh + (((rc >> 1) != 0) ? (1.0f / 128.0f) : (-1.0f / 128.0f));
        float gw = sw + (((rc & 1) != 0) ? (1.0f / 128.0f) : (-1.0f / 128.0f));
        const float lim = 1.0f - 1e-6f;
        gh = fminf(fmaxf(gh, -lim), lim);
        gw = fminf(fmaxf(gw, -lim), lim);
        int iy = (int)rintf(((gh + 1.0f) * 128.0f - 1.0f) * 0.5f);  // round-half-even
        int ix = (int)rintf(((gw + 1.0f) * 128.0f - 1.0f) * 0.5f);
        iy = iy < 0 ? 0 : (iy > 127 ? 127 : iy);
        ix = ix < 0 ? 0 : (ix > 127 ? 127 : ix);
        float cy = (iy + 0.5f) * (2.0f / 128.0f) - 1.0f;
        float cx = (ix + 0.5f) * (2.0f / 128.0f) - 1.0f;
        float rh = (sh - cy) * 128.0f;
        float rw = (sw - cx) * 128.0f;
        sCell[t] = (iy << 7) + ix;
        sRelH[t] = rh; sRelW[t] = rw;
        sArea[t] = fabsf(rh * rw);
    }
    sWh[t] = mw0[576 * 256 + t];
    sWw[t] = mw0[577 * 256 + t];
    __syncthreads();

    // layer 1: t1 = relu(A_pre[cell] + rel_h*W0[576] + rel_w*W0[577])
    {
        int s = t >> 2, nb = (t & 3) << 6;
        float rh = sRelH[s], rw = sRelW[s];
        const float* ap = apre + ((size_t)sCell[s] << 8) + nb;
        int mt = s >> 4, rr = s & 15;
        #pragma unroll
        for (int n = 0; n < 64; n += 4) {
            int col = nb + n;
            float4v ld = *(const float4v*)(ap + n);
            half4 hv;
            #pragma unroll
            for (int kk = 0; kk < 4; ++kk) {
                float v = ld[kk] + rh * sWh[col + kk] + rw * sWw[col + kk];
                hv[kk] = (_Float16)fmaxf(v, 0.0f);
            }
            *(half4*)(act + (((mt * 8 + (col >> 5)) * 64
                              + ((col >> 3) & 3) * 16 + rr) * 8 + (col & 7))) = hv;
        }
    }
    __syncthreads();

    int wave = t >> 6, lane = t & 63, q = lane >> 4, r = lane & 15;

    // hidden layers: each wave does all 64 rows x its 64-col quarter (4x4 frag tiles)
    float4v acc[4][4];
    #pragma unroll 1
    for (int l = 0; l < 3; ++l) {
        #pragma unroll
        for (int mt = 0; mt < 4; ++mt)
            #pragma unroll
            for (int nt = 0; nt < 4; ++nt)
                acc[mt][nt] = (float4v){0.f, 0.f, 0.f, 0.f};
        const _Float16* pw = pwm + l * 65536;
        for (int kc = 0; kc < 8; ++kc) {
            half8 A[4], B[4];
            #pragma unroll
            for (int mt = 0; mt < 4; ++mt)
                A[mt] = *(const half8*)(act + (((mt * 8 + kc) * 64 + lane) << 3));
            #pragma unroll
            for (int nt = 0; nt < 4; ++nt)
                B[nt] = *(const half8*)(pw + ((((wave * 4 + nt) * 8 + kc) * 64 + lane) << 3));
            #pragma unroll
            for (int mt = 0; mt < 4; ++mt)
                #pragma unroll
                for (int nt = 0; nt < 4; ++nt)
                    acc[mt][nt] = __builtin_amdgcn_mfma_f32_16x16x32_f16(
                        A[mt], B[nt], acc[mt][nt], 0, 0, 0);
        }
        const float* mb = (l == 0) ? mb1 : ((l == 1) ? mb2 : mb3);
        float bv[4];
        #pragma unroll
        for (int nt = 0; nt < 4; ++nt)
            bv[nt] = mb[(wave << 6) + nt * 16 + r];
        __syncthreads();   // all waves done reading act
        #pragma unroll
        for (int mt = 0; mt < 4; ++mt)
            #pragma unroll
            for (int nt = 0; nt < 4; ++nt) {
                // out row = mt*16 + q*4 + reg, col = wave*64 + nt*16 + r
                int kcp = (wave << 1) + (nt >> 1);
                int qp  = ((nt & 1) << 1) + (r >> 3);
                int base = ((mt * 8 + kcp) * 64 + qp * 16 + (q << 2)) * 8 + (r & 7);
                #pragma unroll
                for (int reg = 0; reg < 4; ++reg) {
                    float v = fmaxf(acc[mt][nt][reg] + bv[nt], 0.0f);
                    act[base + reg * 8] = (_Float16)v;
                }
            }
        __syncthreads();
    }

    // final layer: wave handles rows 16w..16w+15; D rows = 4 samples of pixel (wave*4+q)
    float4v af = {0.f, 0.f, 0.f, 0.f};
    #pragma unroll
    for (int kc = 0; kc < 8; ++kc) {
        half8 A = *(const half8*)(act + (((wave * 8 + kc) * 64 + lane) << 3));
        half8 B = *(const half8*)(pw4 + ((kc * 64 + lane) << 3));
        af = __builtin_amdgcn_mfma_f32_16x16x32_f16(A, B, af, 0, 0, 0);
    }
    if (r < 3) {   // reg rc holds pred[pixel=wave*4+q][rc][ch=r]
        float b4 = mb4[r];
        int lp = (wave << 2) + q;
        float a0 = sArea[lp * 4 + 0], a1 = sArea[lp * 4 + 1];
        float a2 = sArea[lp * 4 + 2], a3 = sArea[lp * 4 + 3];
        float tot = a0 + a1 + a2 + a3 + 1e-9f;
        float num = (af[0] + b4) * a3 + (af[1] + b4) * a2
                  + (af[2] + b4) * a1 + (af[3] + b4) * a0;
        float v = num / tot;
        v = fminf(fmaxf(v, 0.0f), 1.0f);
        out[r * 262144 + p0 + lp] = v;
    }
}

extern "C" void kernel_launch(void* const* d_in, const int* in_sizes, int n_in,
                              void* d_out, int out_size, void* d_ws, size_t ws_size,
                              hipStream_t stream) {
    (void)in_sizes; (void)n_in; (void)out_size; (void)ws_size;
    const float* x      = (const float*)d_in[0];
    const float* head_w = (const float*)d_in[2];
    const float* head_b = (const float*)d_in[3];
    const float* rb_w   = (const float*)d_in[4];
    const float* rb_b   = (const float*)d_in[5];
    const float* tail_w = (const float*)d_in[6];
    const float* tail_b = (const float*)d_in[7];
    const float* mw0    = (const float*)d_in[8];
    const float* mb0    = (const float*)d_in[9];
    const float* mw1    = (const float*)d_in[10];
    const float* mb1    = (const float*)d_in[11];
    const float* mw2    = (const float*)d_in[12];
    const float* mb2    = (const float*)d_in[13];
    const float* mw3    = (const float*)d_in[14];
    const float* mb3    = (const float*)d_in[15];
    const float* mw4    = (const float*)d_in[16];
    const float* mb4    = (const float*)d_in[17];
    float* out = (float*)d_out;

    char* w = (char*)d_ws;
    auto take = [&](size_t n) { char* p = w; w += (n + 255) & ~(size_t)255; return p; };
    _Float16* pwc  = (_Float16*)take(33u * 36864u * 2u);          // packed conv weights
    _Float16* pw0  = (_Float16*)take(147456u * 2u);               // packed stage-A weights
    _Float16* pwm  = (_Float16*)take(200704u * 2u);               // packed mw1-3 + padded mw4
    float*    b0p  = (float*)take(256u * 4u);
    _Float16* h0   = (_Float16*)take((size_t)NPIX * 64u * 2u);
    _Float16* hbuf = (_Float16*)take((size_t)NPIX * 64u * 2u);
    _Float16* tbuf = (_Float16*)take((size_t)NPIX * 64u * 2u);
    _Float16* feat = (_Float16*)take((size_t)NPIX * 64u * 2u);
    float*    apre = (float*)take((size_t)NPIX * 256u * 4u);      // 16 MB

    pack_conv_w<<<4608, 256, 0, stream>>>(rb_w, pwc, 32);
    pack_conv_w<<<144, 256, 0, stream>>>(tail_w, pwc + 32 * 36864, 1);
    pack_w0<<<576, 256, 0, stream>>>(mw0, pw0);
    pack_mlp<<<784, 256, 0, stream>>>(mw1, mw2, mw3, mw4, pwm);
    make_b0p<<<1, 256, 0, stream>>>(mb0, mw0, b0p);
    head_conv<<<4096, 256, 0, stream>>>(x, head_w, head_b, h0);

    for (int i = 0; i < 16; ++i) {
        const _Float16* hin = (i == 0) ? h0 : hbuf;
        conv_mfma_r<4, 2, true, false, false><<<512, 256, 0, stream>>>(
            hin, pwc + (2 * i) * 36864, rb_b + i * 128, nullptr, tbuf, nullptr);
        conv_mfma_r<4, 2, false, true, false><<<512, 256, 0, stream>>>(
            tbuf, pwc + (2 * i + 1) * 36864, rb_b + i * 128 + 64, hin, hbuf, nullptr);
    }
    // feat64 = h0 + tail(hb)
    conv_mfma_r<4, 2, false, true, false><<<512, 256, 0, stream>>>(
        hbuf, pwc + 32 * 36864, tail_b, h0, feat, nullptr);
    // stage A: A_pre[cell][256] = im2col(feat) @ mw0[:576] + b0'   (just a 64->256 conv)
    conv_mfma_r<16, 4, false, false, true><<<1024, 256, 0, stream>>>(
        feat, pw0, b0p, nullptr, nullptr, apre);

    mlp_kernel<<<16384, 256, 0, stream>>>(apre, mw0, mb1, mb2, mb3, mb4,
                                          pwm, pwm + 196608, out);
}